// Round 3
// baseline (2478.155 us; speedup 1.0000x reference)
//
#include <hip/hip_runtime.h>

#define NN 50000
#define NE 800000
#define DD 128

__device__ __forceinline__ int clampn(int v) {
    return v < 0 ? 0 : (v >= NN ? NN - 1 : v);
}

// ---- degree histogram (indegree; +1 self loop added at use) ----
__global__ __launch_bounds__(256) void k_deg(const int* __restrict__ dst,
                                             int* __restrict__ deg, int E) {
    int i = blockIdx.x * 256 + threadIdx.x;
    if (i < E) atomicAdd(&deg[clampn(dst[i])], 1);
}

// ---- h' = (x @ W) * rsqrt(deg+1), all f32. 32 rows/block, 4x4 register tile ----
__global__ __launch_bounds__(256) void k_gemmf(const float* __restrict__ x,
                                               const float* __restrict__ W,
                                               const int* __restrict__ deg,
                                               float* __restrict__ hp, int n) {
    __shared__ float wl[DD * DD];     // 64 KB: W[k][c]
    __shared__ float xs[32 * DD];     // 16 KB: x rows
    int tid = threadIdx.x;
    int base = blockIdx.x * 32;

    // stage W (16384 floats) via float4
    const float4* W4 = reinterpret_cast<const float4*>(W);
    float4* wl4 = reinterpret_cast<float4*>(wl);
    for (int it = 0; it < 16; ++it) wl4[it * 256 + tid] = W4[it * 256 + tid];
    // stage 32 x-rows (4096 floats)
    float4* xs4 = reinterpret_cast<float4*>(xs);
    const float4* x4p = reinterpret_cast<const float4*>(x);
    for (int it = 0; it < 4; ++it) {
        int idx = it * 256 + tid;            // float4 index within slab (32*32)
        int row = idx >> 5, col4 = idx & 31; // row in [0,32), col4 in [0,32)
        int r = base + row;
        xs4[idx] = (r < n) ? x4p[(long)r * 32 + col4] : float4{0.f, 0.f, 0.f, 0.f};
    }
    __syncthreads();

    int cg = tid & 31, rg = tid >> 5;        // 32 col-groups x 8 row-groups
    int c0 = cg * 4;
    float acc[4][4] = {};
    for (int kk = 0; kk < 32; ++kk) {
        float4 xv[4], wv[4];
#pragma unroll
        for (int i = 0; i < 4; ++i)
            xv[i] = *reinterpret_cast<const float4*>(&xs[(rg * 4 + i) * DD + kk * 4]);
#pragma unroll
        for (int q = 0; q < 4; ++q)
            wv[q] = *reinterpret_cast<const float4*>(&wl[(kk * 4 + q) * DD + c0]);
#pragma unroll
        for (int i = 0; i < 4; ++i) {
#pragma unroll
            for (int j = 0; j < 4; ++j) {
                acc[i][j] += xv[i].x * (&wv[0].x)[j]
                           + xv[i].y * (&wv[1].x)[j]
                           + xv[i].z * (&wv[2].x)[j]
                           + xv[i].w * (&wv[3].x)[j];
            }
        }
    }
#pragma unroll
    for (int i = 0; i < 4; ++i) {
        int r = base + rg * 4 + i;
        if (r < n) {
            float dv = rsqrtf((float)(deg[r] + 1));
            float4 o = {acc[i][0] * dv, acc[i][1] * dv, acc[i][2] * dv, acc[i][3] * dv};
            *reinterpret_cast<float4*>(&hp[(long)r * DD + c0]) = o;
        }
    }
}

// ---- agg[dst] += h'[src] : one wave per edge, lane handles 2 channels ----
__global__ __launch_bounds__(256) void k_scatter(const int* __restrict__ src,
                                                 const int* __restrict__ dst,
                                                 const float* __restrict__ hp,
                                                 float* __restrict__ agg, int E) {
    int gw = (blockIdx.x * 256 + threadIdx.x) >> 6;
    if (gw >= E) return;
    int lane = threadIdx.x & 63;
    int s = clampn(src[gw]), d = clampn(dst[gw]);
    float2 v = *reinterpret_cast<const float2*>(hp + (long)s * DD + lane * 2);
    unsafeAtomicAdd(&agg[(long)d * DD + lane * 2], v.x);
    unsafeAtomicAdd(&agg[(long)d * DD + lane * 2 + 1], v.y);
}

// ---- g[c] += sum_v relu(dinv[v]*(agg[v][c]+h'[v][c]) + b[c]) ----
__global__ __launch_bounds__(256) void k_pool(const float* __restrict__ agg,
                                              const float* __restrict__ hp,
                                              const int* __restrict__ deg,
                                              const float* __restrict__ bias,
                                              float* __restrict__ gout, int n) {
    int c = threadIdx.x & 127;
    int half = threadIdx.x >> 7;
    float bv = bias[c];
    float acc = 0.f;
    int per = (n + gridDim.x - 1) / gridDim.x;
    int r0 = blockIdx.x * per;
    int r1 = r0 + per; if (r1 > n) r1 = n;
    for (int r = r0 + half; r < r1; r += 2) {
        float dv = rsqrtf((float)(deg[r] + 1));
        float v = dv * (agg[(long)r * DD + c] + hp[(long)r * DD + c]) + bv;
        acc += fmaxf(v, 0.f);
    }
    __shared__ float red[256];
    red[threadIdx.x] = acc;
    __syncthreads();
    if (half == 0) unsafeAtomicAdd(&gout[c], red[c] + red[128 + c]);
}

// ---- head MLP: attention over 3 pooled signatures + FiLM gates ----
__global__ __launch_bounds__(128) void k_head(const float* __restrict__ g,
    const float* __restrict__ w1, const float* __restrict__ b1,
    const float* __restrict__ w2, const float* __restrict__ b2,
    const float* __restrict__ w3, const float* __restrict__ b3,
    const float* __restrict__ f1w, const float* __restrict__ f1b,
    const float* __restrict__ f2w, const float* __restrict__ f2b,
    float* __restrict__ out) {
    __shared__ float xin[384], h1[128], h2[128], aw[3], xctx[128];
    int t = threadIdx.x;
    for (int i = t; i < 384; i += 128) xin[i] = g[i];
    __syncthreads();
    float s = b1[t];
    for (int j = 0; j < 384; ++j) s += xin[j] * w1[t * 384 + j];
    h1[t] = fmaxf(s, 0.f);
    __syncthreads();
    s = b2[t];
    for (int j = 0; j < 128; ++j) s += h1[j] * w2[t * 128 + j];
    h2[t] = fmaxf(s, 0.f);   // relu(h) feeds fc3
    __syncthreads();
    if (t < 3) {
        float sl = b3[t];
        for (int j = 0; j < 128; ++j) sl += h2[j] * w3[t * 128 + j];
        aw[t] = sl;
    }
    __syncthreads();
    if (t == 0) {
        float mx = fmaxf(aw[0], fmaxf(aw[1], aw[2]));
        float e0 = expf(aw[0] - mx), e1 = expf(aw[1] - mx), e2 = expf(aw[2] - mx);
        float inv = 1.f / (e0 + e1 + e2);
        aw[0] = e0 * inv; aw[1] = e1 * inv; aw[2] = e2 * inv;
    }
    __syncthreads();
    xctx[t] = aw[0] * xin[t] + aw[1] * xin[128 + t] + aw[2] * xin[256 + t];
    __syncthreads();
    float sg = f1b[t], sb = f2b[t];
    for (int j = 0; j < 128; ++j) {
        float xj = xctx[j];
        sg += xj * f1w[t * 128 + j];
        sb += xj * f2w[t * 128 + j];
    }
    out[t]       = tanhf(sg);
    out[128 + t] = tanhf(sb);
}

extern "C" void kernel_launch(void* const* d_in, const int* in_sizes, int n_in,
                              void* d_out, int out_size, void* d_ws, size_t ws_size,
                              hipStream_t stream) {
    (void)in_sizes; (void)n_in; (void)out_size; (void)ws_size;

    const float* x[3]  = {(const float*)d_in[0], (const float*)d_in[1], (const float*)d_in[2]};
    const int*   ei[3] = {(const int*)d_in[3], (const int*)d_in[4], (const int*)d_in[5]};
    const float* cw[3] = {(const float*)d_in[6], (const float*)d_in[8], (const float*)d_in[10]};
    const float* cb[3] = {(const float*)d_in[7], (const float*)d_in[9], (const float*)d_in[11]};

    char* ws = (char*)d_ws;
    float* hp  = (float*)ws;                         // 25,600,000 B
    float* agg = (float*)(ws + 25600000);            // 25,600,000 B
    int*   deg = (int*)  (ws + 51200000);            // 200,000 B
    float* g   = (float*)(ws + 51400000);            // 1,536 B

    hipMemsetAsync(g, 0, 3 * DD * sizeof(float), stream);
    for (int i = 0; i < 3; ++i) {
        hipMemsetAsync(deg, 0, NN * sizeof(int), stream);
        k_deg<<<(NE + 255) / 256, 256, 0, stream>>>(ei[i] + NE, deg, NE);
        k_gemmf<<<(NN + 31) / 32, 256, 0, stream>>>(x[i], cw[i], deg, hp, NN);
        hipMemsetAsync(agg, 0, (size_t)NN * DD * sizeof(float), stream);
        k_scatter<<<(NE * 64 + 255) / 256, 256, 0, stream>>>(ei[i], ei[i] + NE, hp, agg, NE);
        k_pool<<<200, 256, 0, stream>>>(agg, hp, deg, cb[i], g + i * DD, NN);
    }
    k_head<<<1, 128, 0, stream>>>(g,
        (const float*)d_in[12], (const float*)d_in[13],
        (const float*)d_in[14], (const float*)d_in[15],
        (const float*)d_in[16], (const float*)d_in[17],
        (const float*)d_in[18], (const float*)d_in[19],
        (const float*)d_in[20], (const float*)d_in[21],
        (float*)d_out);
}

// Round 4
// 1024.994 us; speedup vs baseline: 2.4177x; 2.4177x over previous
//
#include <hip/hip_runtime.h>

#define NN 50000
#define NE 800000
#define DD 128
#define RPS (NN + 16)   // rowptr stride (ints), 16B-aligned

__device__ __forceinline__ int clampn(int v) {
    return v < 0 ? 0 : (v >= NN ? NN - 1 : v);
}

// ---- batched indegree histogram over the 3 edge lists ----
__global__ __launch_bounds__(256) void k_deg3(const int* __restrict__ e0,
                                              const int* __restrict__ e1,
                                              const int* __restrict__ e2,
                                              int* __restrict__ deg) {
    const int* dst = (blockIdx.y == 0 ? e0 : blockIdx.y == 1 ? e1 : e2) + NE;
    int i = blockIdx.x * 256 + threadIdx.x;
    if (i < NE) atomicAdd(&deg[blockIdx.y * NN + clampn(dst[i])], 1);
}

// ---- batched exclusive scan: deg -> rowptr, cursor (one block per conv) ----
__global__ __launch_bounds__(1024) void k_scan3(const int* __restrict__ deg,
                                                int* __restrict__ rowptr,
                                                int* __restrict__ cursor) {
    __shared__ int part[1024];
    const int* dg = deg + blockIdx.x * NN;
    int* rp = rowptr + blockIdx.x * RPS;
    int* cu = cursor + blockIdx.x * NN;
    int t = threadIdx.x;
    const int CH = (NN + 1023) / 1024;   // 49
    int b = t * CH;
    int e = b + CH; if (e > NN) e = NN; if (b > NN) b = NN;
    int s = 0;
    for (int i = b; i < e; ++i) s += dg[i];
    part[t] = s;
    __syncthreads();
    for (int off = 1; off < 1024; off <<= 1) {
        int v = part[t];
        int u = (t >= off) ? part[t - off] : 0;
        __syncthreads();
        part[t] = v + u;
        __syncthreads();
    }
    int run = (t == 0) ? 0 : part[t - 1];
    for (int i = b; i < e; ++i) {
        rp[i] = run; cu[i] = run;
        run += dg[i];
    }
    if (t == 1023) rp[NN] = part[1023];
}

// ---- batched CSR bucket fill ----
__global__ __launch_bounds__(256) void k_fill3(const int* __restrict__ e0,
                                               const int* __restrict__ e1,
                                               const int* __restrict__ e2,
                                               int* __restrict__ cursor,
                                               int* __restrict__ adj) {
    const int* ei = (blockIdx.y == 0 ? e0 : blockIdx.y == 1 ? e1 : e2);
    int i = blockIdx.x * 256 + threadIdx.x;
    if (i < NE) {
        int d = clampn(ei[NE + i]);
        int pos = atomicAdd(&cursor[blockIdx.y * NN + d], 1);
        adj[blockIdx.y * NE + pos] = clampn(ei[i]);
    }
}

// ---- h' = (x @ W) * rsqrt(deg+1), all f32. 32 rows/block, 4x4 register tile ----
__global__ __launch_bounds__(256) void k_gemmf(const float* __restrict__ x,
                                               const float* __restrict__ W,
                                               const int* __restrict__ deg,
                                               float* __restrict__ hp, int n) {
    __shared__ float wl[DD * DD];     // 64 KB: W[k][c]
    __shared__ float xs[32 * DD];     // 16 KB
    int tid = threadIdx.x;
    int base = blockIdx.x * 32;

    const float4* W4 = reinterpret_cast<const float4*>(W);
    float4* wl4 = reinterpret_cast<float4*>(wl);
    for (int it = 0; it < 16; ++it) wl4[it * 256 + tid] = W4[it * 256 + tid];
    float4* xs4 = reinterpret_cast<float4*>(xs);
    const float4* x4p = reinterpret_cast<const float4*>(x);
    for (int it = 0; it < 4; ++it) {
        int idx = it * 256 + tid;
        int row = idx >> 5, col4 = idx & 31;
        int r = base + row;
        xs4[idx] = (r < n) ? x4p[(long)r * 32 + col4] : float4{0.f, 0.f, 0.f, 0.f};
    }
    __syncthreads();

    int cg = tid & 31, rg = tid >> 5;
    int c0 = cg * 4;
    float acc[4][4] = {};
    for (int kk = 0; kk < 32; ++kk) {
        float4 xv[4], wv[4];
#pragma unroll
        for (int i = 0; i < 4; ++i)
            xv[i] = *reinterpret_cast<const float4*>(&xs[(rg * 4 + i) * DD + kk * 4]);
#pragma unroll
        for (int q = 0; q < 4; ++q)
            wv[q] = *reinterpret_cast<const float4*>(&wl[(kk * 4 + q) * DD + c0]);
#pragma unroll
        for (int i = 0; i < 4; ++i) {
#pragma unroll
            for (int j = 0; j < 4; ++j) {
                acc[i][j] += xv[i].x * (&wv[0].x)[j]
                           + xv[i].y * (&wv[1].x)[j]
                           + xv[i].z * (&wv[2].x)[j]
                           + xv[i].w * (&wv[3].x)[j];
            }
        }
    }
#pragma unroll
    for (int i = 0; i < 4; ++i) {
        int r = base + rg * 4 + i;
        if (r < n) {
            float dv = rsqrtf((float)(deg[r] + 1));
            float4 o = {acc[i][0] * dv, acc[i][1] * dv, acc[i][2] * dv, acc[i][3] * dv};
            *reinterpret_cast<float4*>(&hp[(long)r * DD + c0]) = o;
        }
    }
}

// ---- fused gather + self-loop + relu + pool: one wave per node (strided) ----
__global__ __launch_bounds__(256) void k_gather(const float* __restrict__ hp,
                                                const int* __restrict__ rowptr,
                                                const int* __restrict__ adj,
                                                const int* __restrict__ deg,
                                                const float* __restrict__ bias,
                                                float* __restrict__ gout, int n) {
    int lane = threadIdx.x & 63;
    int wave = threadIdx.x >> 6;
    int wv = blockIdx.x * 4 + wave;
    int stride = gridDim.x * 4;
    const float2* hp2 = reinterpret_cast<const float2*>(hp);
    float2 b2 = reinterpret_cast<const float2*>(bias)[lane];
    float px = 0.f, py = 0.f;
    for (int v = wv; v < n; v += stride) {
        float2 acc = hp2[(long)v * 64 + lane];       // self loop
        int beg = rowptr[v], end = rowptr[v + 1];
        for (int j = beg; j < end; ++j) {
            int s = adj[j];
            float2 t = hp2[(long)s * 64 + lane];
            acc.x += t.x; acc.y += t.y;
        }
        float dv = rsqrtf((float)(deg[v] + 1));
        px += fmaxf(dv * acc.x + b2.x, 0.f);
        py += fmaxf(dv * acc.y + b2.y, 0.f);
    }
    __shared__ float red[4][DD];
    red[wave][lane * 2] = px;
    red[wave][lane * 2 + 1] = py;
    __syncthreads();
    int t = threadIdx.x;
    if (t < DD)
        unsafeAtomicAdd(&gout[t], red[0][t] + red[1][t] + red[2][t] + red[3][t]);
}

// ---- head MLP: attention over 3 pooled signatures + FiLM gates ----
__global__ __launch_bounds__(128) void k_head(const float* __restrict__ g,
    const float* __restrict__ w1, const float* __restrict__ b1,
    const float* __restrict__ w2, const float* __restrict__ b2,
    const float* __restrict__ w3, const float* __restrict__ b3,
    const float* __restrict__ f1w, const float* __restrict__ f1b,
    const float* __restrict__ f2w, const float* __restrict__ f2b,
    float* __restrict__ out) {
    __shared__ float xin[384], h1[128], h2[128], aw[3], xctx[128];
    int t = threadIdx.x;
    for (int i = t; i < 384; i += 128) xin[i] = g[i];
    __syncthreads();
    float s = b1[t];
    for (int j = 0; j < 384; ++j) s += xin[j] * w1[t * 384 + j];
    h1[t] = fmaxf(s, 0.f);
    __syncthreads();
    s = b2[t];
    for (int j = 0; j < 128; ++j) s += h1[j] * w2[t * 128 + j];
    h2[t] = fmaxf(s, 0.f);
    __syncthreads();
    if (t < 3) {
        float sl = b3[t];
        for (int j = 0; j < 128; ++j) sl += h2[j] * w3[t * 128 + j];
        aw[t] = sl;
    }
    __syncthreads();
    if (t == 0) {
        float mx = fmaxf(aw[0], fmaxf(aw[1], aw[2]));
        float e0 = expf(aw[0] - mx), e1 = expf(aw[1] - mx), e2 = expf(aw[2] - mx);
        float inv = 1.f / (e0 + e1 + e2);
        aw[0] = e0 * inv; aw[1] = e1 * inv; aw[2] = e2 * inv;
    }
    __syncthreads();
    xctx[t] = aw[0] * xin[t] + aw[1] * xin[128 + t] + aw[2] * xin[256 + t];
    __syncthreads();
    float sg = f1b[t], sb = f2b[t];
    for (int j = 0; j < 128; ++j) {
        float xj = xctx[j];
        sg += xj * f1w[t * 128 + j];
        sb += xj * f2w[t * 128 + j];
    }
    out[t]       = tanhf(sg);
    out[128 + t] = tanhf(sb);
}

extern "C" void kernel_launch(void* const* d_in, const int* in_sizes, int n_in,
                              void* d_out, int out_size, void* d_ws, size_t ws_size,
                              hipStream_t stream) {
    (void)in_sizes; (void)n_in; (void)out_size; (void)ws_size;

    const float* x[3]  = {(const float*)d_in[0], (const float*)d_in[1], (const float*)d_in[2]};
    const int*   ei[3] = {(const int*)d_in[3], (const int*)d_in[4], (const int*)d_in[5]};
    const float* cw[3] = {(const float*)d_in[6], (const float*)d_in[8], (const float*)d_in[10]};
    const float* cb[3] = {(const float*)d_in[7], (const float*)d_in[9], (const float*)d_in[11]};

    char* ws = (char*)d_ws;
    float* hp     = (float*)ws;                       // 25,600,000
    int*   deg    = (int*)  (ws + 25600000);          //    600,000 (3x NN)
    int*   rowptr = (int*)  (ws + 26200000);          //    600,192 (3x RPS)
    int*   cursor = (int*)  (ws + 26814400);          //    600,000 (3x NN)
    int*   adj    = (int*)  (ws + 27414400);          //  9,600,000 (3x NE)
    float* g      = (float*)(ws + 37014400);          //      1,536

    hipMemsetAsync(deg, 0, 3 * NN * sizeof(int), stream);
    hipMemsetAsync(g, 0, 3 * DD * sizeof(float), stream);

    dim3 egrid((NE + 255) / 256, 3);
    k_deg3 <<<egrid, 256, 0, stream>>>(ei[0], ei[1], ei[2], deg);
    k_scan3<<<3, 1024, 0, stream>>>(deg, rowptr, cursor);
    k_fill3<<<egrid, 256, 0, stream>>>(ei[0], ei[1], ei[2], cursor, adj);

    for (int i = 0; i < 3; ++i) {
        k_gemmf <<<(NN + 31) / 32, 256, 0, stream>>>(x[i], cw[i], deg + i * NN, hp, NN);
        k_gather<<<2048, 256, 0, stream>>>(hp, rowptr + i * RPS, adj + i * NE,
                                           deg + i * NN, cb[i], g + i * DD, NN);
    }
    k_head<<<1, 128, 0, stream>>>(g,
        (const float*)d_in[12], (const float*)d_in[13],
        (const float*)d_in[14], (const float*)d_in[15],
        (const float*)d_in[16], (const float*)d_in[17],
        (const float*)d_in[18], (const float*)d_in[19],
        (const float*)d_in[20], (const float*)d_in[21],
        (float*)d_out);
}